// Round 1
// baseline (167.962 us; speedup 1.0000x reference)
//
#include <hip/hip_runtime.h>
#include <math.h>

constexpr int Bn = 8, Nn = 4096, Cn = 1024, Hn = 256, Kn = 3;
constexpr float EPS = 1e-5f;
constexpr int ROWS = 64;

// ---------------- kernel 1: column sums over N (for the mean) ----------------
__global__ __launch_bounds__(256) void k_colsum(const float* __restrict__ x,
                                                float* __restrict__ ctxsum) {
    int blk = blockIdx.x;                 // Bn * (Nn/ROWS) blocks
    int b  = blk / (Nn / ROWS);
    int n0 = (blk % (Nn / ROWS)) * ROWS;
    int c  = threadIdx.x * 4;
    const float* p = x + ((size_t)b * Nn + n0) * Cn + c;
    float4 acc = make_float4(0.f, 0.f, 0.f, 0.f);
    #pragma unroll 4
    for (int r = 0; r < ROWS; ++r) {
        float4 v = *reinterpret_cast<const float4*>(p + (size_t)r * Cn);
        acc.x += v.x; acc.y += v.y; acc.z += v.z; acc.w += v.w;
    }
    float* d = ctxsum + b * Cn + c;
    atomicAdd(d + 0, acc.x);
    atomicAdd(d + 1, acc.y);
    atomicAdd(d + 2, acc.z);
    atomicAdd(d + 3, acc.w);
}

// ---------------- kernel 2: h = gelu(ctx @ W1 + b1), exact erf GELU ----------
__global__ __launch_bounds__(256) void k_mlp1(const float* __restrict__ ctxsum,
                                              const float* __restrict__ W1,
                                              const float* __restrict__ b1,
                                              float* __restrict__ h) {
    int b = blockIdx.x;        // Bn blocks
    int j = threadIdx.x;       // Hn == 256 threads
    const float invN = 1.0f / (float)Nn;
    const float* cs = ctxsum + b * Cn;
    float acc = b1[j];
    #pragma unroll 8
    for (int c = 0; c < Cn; ++c)
        acc = fmaf(cs[c] * invN, W1[c * Hn + j], acc);
    h[b * Hn + j] = 0.5f * acc * (1.0f + erff(acc * 0.70710678118654752440f));
}

// ---------------- kernel 3: kernels = h @ W2 + b2, stored [B][K][C] ----------
__global__ __launch_bounds__(256) void k_mlp2(const float* __restrict__ h,
                                              const float* __restrict__ W2,
                                              const float* __restrict__ b2,
                                              float* __restrict__ kern) {
    int b = blockIdx.y;
    int m = blockIdx.x * 256 + threadIdx.x;    // [0, Cn*Kn)
    const float* hb = h + b * Hn;
    float acc = b2[m];
    #pragma unroll 8
    for (int j = 0; j < Hn; ++j)
        acc = fmaf(hb[j], W2[j * (Cn * Kn) + m], acc);
    int c = m / Kn, jj = m - c * Kn;
    kern[((size_t)b * Kn + jj) * Cn + c] = acc;   // transposed for coalesced conv reads
}

// ---------------- kernel 4: depthwise conv + residual + LayerNorm ------------
__global__ __launch_bounds__(256) void k_conv_ln(const float* __restrict__ x,
                                                 const float* __restrict__ kern,
                                                 const float* __restrict__ gamma,
                                                 const float* __restrict__ beta,
                                                 float* __restrict__ out) {
    int blk = blockIdx.x;          // Bn*Nn blocks; n fastest for L2 locality
    int b = blk / Nn, n = blk % Nn;
    int c = threadIdx.x * 4;
    size_t row = ((size_t)b * Nn + n) * Cn + c;

    float4 xc = *reinterpret_cast<const float4*>(x + row);
    float4 xm = make_float4(0.f, 0.f, 0.f, 0.f);
    float4 xp = make_float4(0.f, 0.f, 0.f, 0.f);
    if (n > 0)      xm = *reinterpret_cast<const float4*>(x + row - Cn);
    if (n < Nn - 1) xp = *reinterpret_cast<const float4*>(x + row + Cn);

    const float* kb = kern + (size_t)b * Kn * Cn + c;
    float4 k0 = *reinterpret_cast<const float4*>(kb);
    float4 k1 = *reinterpret_cast<const float4*>(kb + Cn);
    float4 k2 = *reinterpret_cast<const float4*>(kb + 2 * Cn);

    float4 y;
    y.x = fmaf(k0.x, xm.x, fmaf(k1.x, xc.x, fmaf(k2.x, xp.x, xc.x)));
    y.y = fmaf(k0.y, xm.y, fmaf(k1.y, xc.y, fmaf(k2.y, xp.y, xc.y)));
    y.z = fmaf(k0.z, xm.z, fmaf(k1.z, xc.z, fmaf(k2.z, xp.z, xc.z)));
    y.w = fmaf(k0.w, xm.w, fmaf(k1.w, xc.w, fmaf(k2.w, xp.w, xc.w)));

    // block reduction for sum and sum-of-squares over the 1024 channels
    float s  = y.x + y.y + y.z + y.w;
    float s2 = y.x * y.x + y.y * y.y + y.z * y.z + y.w * y.w;
    #pragma unroll
    for (int off = 32; off > 0; off >>= 1) {
        s  += __shfl_down(s, off, 64);
        s2 += __shfl_down(s2, off, 64);
    }
    __shared__ float sm[8];
    int wave = threadIdx.x >> 6;
    if ((threadIdx.x & 63) == 0) { sm[wave] = s; sm[4 + wave] = s2; }
    __syncthreads();
    s  = sm[0] + sm[1] + sm[2] + sm[3];
    s2 = sm[4] + sm[5] + sm[6] + sm[7];

    float mu   = s * (1.0f / (float)Cn);
    float var  = fmaf(-mu, mu, s2 * (1.0f / (float)Cn));
    float rstd = rsqrtf(var + EPS);

    float4 g  = *reinterpret_cast<const float4*>(gamma + c);
    float4 be = *reinterpret_cast<const float4*>(beta + c);
    float4 o;
    o.x = fmaf((y.x - mu) * rstd, g.x, be.x);
    o.y = fmaf((y.y - mu) * rstd, g.y, be.y);
    o.z = fmaf((y.z - mu) * rstd, g.z, be.z);
    o.w = fmaf((y.w - mu) * rstd, g.w, be.w);
    *reinterpret_cast<float4*>(out + row) = o;
}

extern "C" void kernel_launch(void* const* d_in, const int* in_sizes, int n_in,
                              void* d_out, int out_size, void* d_ws, size_t ws_size,
                              hipStream_t stream) {
    const float* x     = (const float*)d_in[0];
    const float* W1    = (const float*)d_in[1];
    const float* b1    = (const float*)d_in[2];
    const float* W2    = (const float*)d_in[3];
    const float* b2    = (const float*)d_in[4];
    const float* gamma = (const float*)d_in[5];
    const float* beta  = (const float*)d_in[6];
    float* out = (float*)d_out;

    float* ws     = (float*)d_ws;
    float* ctxsum = ws;                       // Bn*Cn  = 8192 floats
    float* h      = ctxsum + Bn * Cn;         // Bn*Hn  = 2048 floats
    float* kern   = h + Bn * Hn;              // Bn*Kn*Cn = 24576 floats

    hipMemsetAsync(ctxsum, 0, Bn * Cn * sizeof(float), stream);
    k_colsum<<<Bn * (Nn / ROWS), 256, 0, stream>>>(x, ctxsum);
    k_mlp1<<<Bn, Hn, 0, stream>>>(ctxsum, W1, b1, h);
    dim3 g2(Cn * Kn / 256, Bn);
    k_mlp2<<<g2, 256, 0, stream>>>(h, W2, b2, kern);
    k_conv_ln<<<Bn * Nn, 256, 0, stream>>>(x, kern, gamma, beta, out);
}

// Round 2
// 105.709 us; speedup vs baseline: 1.5889x; 1.5889x over previous
//
#include <hip/hip_runtime.h>
#include <math.h>

constexpr int Bn = 8, Nn = 4096, Cn = 1024, Hn = 256, Kn = 3;
constexpr float EPS = 1e-5f;
constexpr int ROWS = 64;                 // rows per colsum block
constexpr int NBLK = Nn / ROWS;          // 64 partial blocks per batch

// ---------------- kernel 1: partial column sums over N (no atomics) ----------
__global__ __launch_bounds__(256) void k_colsum(const float* __restrict__ x,
                                                float* __restrict__ partial) {
    int blk = blockIdx.x;                 // Bn * NBLK = 512 blocks
    int b  = blk / NBLK;
    int n0 = (blk % NBLK) * ROWS;
    int c  = threadIdx.x * 4;
    const float* p = x + ((size_t)b * Nn + n0) * Cn + c;
    float4 acc = make_float4(0.f, 0.f, 0.f, 0.f);
    #pragma unroll 8
    for (int r = 0; r < ROWS; ++r) {
        float4 v = *reinterpret_cast<const float4*>(p + (size_t)r * Cn);
        acc.x += v.x; acc.y += v.y; acc.z += v.z; acc.w += v.w;
    }
    *reinterpret_cast<float4*>(partial + (size_t)blk * Cn + c) = acc;
}

// ------- kernel 2: ctx reduce + h = gelu(ctx @ W1 + b1); 4 j-slices/b -------
__global__ __launch_bounds__(256) void k_mlp1(const float* __restrict__ partial,
                                              const float* __restrict__ W1,
                                              const float* __restrict__ b1,
                                              float* __restrict__ h) {
    int b = blockIdx.x >> 2;             // 32 blocks: b*4 + slice
    int s = blockIdx.x & 3;
    int t = threadIdx.x;

    __shared__ float ctx[Cn];
    __shared__ float red[4][64];

    // phase 1: reduce 64 partials for 4 channels per thread
    const float invN = 1.0f / (float)Nn;
    const float* pp = partial + (size_t)b * NBLK * Cn;
    float a0 = 0.f, a1 = 0.f, a2 = 0.f, a3 = 0.f;
    for (int p = 0; p < NBLK; ++p) {
        const float* row = pp + (size_t)p * Cn;
        a0 += row[t];
        a1 += row[t + 256];
        a2 += row[t + 512];
        a3 += row[t + 768];
    }
    ctx[t]       = a0 * invN;
    ctx[t + 256] = a1 * invN;
    ctx[t + 512] = a2 * invN;
    ctx[t + 768] = a3 * invN;
    __syncthreads();

    // phase 2: split-K GEMV for 64 columns of W1
    int jl = t & 63, kq = t >> 6;
    int j  = s * 64 + jl;
    const float* w1 = W1 + j;
    float a = 0.f;
    int c0 = kq * 256;
    #pragma unroll 4
    for (int cc = 0; cc < 256; ++cc)
        a = fmaf(ctx[c0 + cc], w1[(size_t)(c0 + cc) * Hn], a);
    red[kq][jl] = a;
    __syncthreads();

    if (t < 64) {
        int jj = s * 64 + t;
        float v = red[0][t] + red[1][t] + red[2][t] + red[3][t] + b1[jj];
        h[b * Hn + jj] = 0.5f * v * (1.0f + erff(v * 0.70710678118654752440f));
    }
}

// ------- kernel 3: kernels = h @ W2 + b2, stored transposed [B][K][C] -------
__global__ __launch_bounds__(256) void k_mlp2(const float* __restrict__ h,
                                              const float* __restrict__ W2,
                                              const float* __restrict__ b2,
                                              float* __restrict__ kern) {
    int b = blockIdx.y;                   // 8
    int m = blockIdx.x * 256 + threadIdx.x;  // 12 x-blocks -> [0, Cn*Kn)
    __shared__ float hs[Hn];
    hs[threadIdx.x] = h[b * Hn + threadIdx.x];
    __syncthreads();
    float a0 = b2[m], a1 = 0.f, a2 = 0.f, a3 = 0.f;
    const float* w2 = W2 + m;
    #pragma unroll 4
    for (int j = 0; j < Hn; j += 4) {
        a0 = fmaf(hs[j],     w2[(size_t)j       * (Cn * Kn)], a0);
        a1 = fmaf(hs[j + 1], w2[(size_t)(j + 1) * (Cn * Kn)], a1);
        a2 = fmaf(hs[j + 2], w2[(size_t)(j + 2) * (Cn * Kn)], a2);
        a3 = fmaf(hs[j + 3], w2[(size_t)(j + 3) * (Cn * Kn)], a3);
    }
    float val = (a0 + a1) + (a2 + a3);
    int c = m / Kn, k = m - c * Kn;
    kern[((size_t)b * Kn + k) * Cn + c] = val;
}

// ------- kernel 4: depthwise conv + residual + LayerNorm; 1 wave per row ----
__global__ __launch_bounds__(256) void k_conv_ln(const float* __restrict__ x,
                                                 const float* __restrict__ kern,
                                                 const float* __restrict__ gamma,
                                                 const float* __restrict__ beta,
                                                 float* __restrict__ out) {
    int r = blockIdx.x * 4 + (threadIdx.x >> 6);   // global row, Bn*Nn total
    int b = r >> 12;                                // Nn == 4096
    int n = r & (Nn - 1);
    int lane = threadIdx.x & 63;

    const float4* xc4 = reinterpret_cast<const float4*>(x + (size_t)r * Cn);
    const float4* xm4 = xc4 - (Cn / 4);
    const float4* xp4 = xc4 + (Cn / 4);
    const float4* k04 = reinterpret_cast<const float4*>(kern + (size_t)b * Kn * Cn);
    const float4* k14 = k04 + (Cn / 4);
    const float4* k24 = k14 + (Cn / 4);

    bool hasM = (n > 0), hasP = (n < Nn - 1);
    float4 y[4];
    float s = 0.f, s2 = 0.f;
    #pragma unroll
    for (int k = 0; k < 4; ++k) {
        int ci = lane + (k << 6);                   // float4 index within row
        float4 xc = xc4[ci];
        float4 xm = hasM ? xm4[ci] : make_float4(0.f, 0.f, 0.f, 0.f);
        float4 xp = hasP ? xp4[ci] : make_float4(0.f, 0.f, 0.f, 0.f);
        float4 k0 = k04[ci], k1 = k14[ci], k2 = k24[ci];
        float4 v;
        v.x = fmaf(k0.x, xm.x, fmaf(k1.x, xc.x, fmaf(k2.x, xp.x, xc.x)));
        v.y = fmaf(k0.y, xm.y, fmaf(k1.y, xc.y, fmaf(k2.y, xp.y, xc.y)));
        v.z = fmaf(k0.z, xm.z, fmaf(k1.z, xc.z, fmaf(k2.z, xp.z, xc.z)));
        v.w = fmaf(k0.w, xm.w, fmaf(k1.w, xc.w, fmaf(k2.w, xp.w, xc.w)));
        y[k] = v;
        s  += (v.x + v.y) + (v.z + v.w);
        s2 += fmaf(v.x, v.x, fmaf(v.y, v.y, fmaf(v.z, v.z, v.w * v.w)));
    }

    // 64-lane butterfly reduction (no LDS, no barrier)
    #pragma unroll
    for (int off = 1; off < 64; off <<= 1) {
        s  += __shfl_xor(s,  off, 64);
        s2 += __shfl_xor(s2, off, 64);
    }

    float mu   = s * (1.0f / (float)Cn);
    float var  = fmaf(-mu, mu, s2 * (1.0f / (float)Cn));
    float rstd = rsqrtf(var + EPS);

    const float4* g4  = reinterpret_cast<const float4*>(gamma);
    const float4* be4 = reinterpret_cast<const float4*>(beta);
    float4* o4 = reinterpret_cast<float4*>(out + (size_t)r * Cn);
    #pragma unroll
    for (int k = 0; k < 4; ++k) {
        int ci = lane + (k << 6);
        float4 g = g4[ci], be = be4[ci], v = y[k], o;
        o.x = fmaf((v.x - mu) * rstd, g.x, be.x);
        o.y = fmaf((v.y - mu) * rstd, g.y, be.y);
        o.z = fmaf((v.z - mu) * rstd, g.z, be.z);
        o.w = fmaf((v.w - mu) * rstd, g.w, be.w);
        o4[ci] = o;
    }
}

extern "C" void kernel_launch(void* const* d_in, const int* in_sizes, int n_in,
                              void* d_out, int out_size, void* d_ws, size_t ws_size,
                              hipStream_t stream) {
    const float* x     = (const float*)d_in[0];
    const float* W1    = (const float*)d_in[1];
    const float* b1    = (const float*)d_in[2];
    const float* W2    = (const float*)d_in[3];
    const float* b2    = (const float*)d_in[4];
    const float* gamma = (const float*)d_in[5];
    const float* beta  = (const float*)d_in[6];
    float* out = (float*)d_out;

    float* ws      = (float*)d_ws;
    float* partial = ws;                                  // 512*1024 = 524288 floats (2 MB)
    float* h       = partial + (size_t)Bn * NBLK * Cn;    // 2048 floats
    float* kern    = h + Bn * Hn;                         // 24576 floats

    k_colsum<<<Bn * NBLK, 256, 0, stream>>>(x, partial);
    k_mlp1<<<Bn * 4, 256, 0, stream>>>(partial, W1, b1, h);
    dim3 g2(Cn * Kn / 256, Bn);
    k_mlp2<<<g2, 256, 0, stream>>>(h, W2, b2, kern);
    k_conv_ln<<<Bn * Nn / 4, 256, 0, stream>>>(x, kern, gamma, beta, out);
}

// Round 3
// 105.172 us; speedup vs baseline: 1.5970x; 1.0051x over previous
//
#include <hip/hip_runtime.h>
#include <math.h>

constexpr int Bn = 8, Nn = 4096, Cn = 1024, Hn = 256, Kn = 3;
constexpr float EPS = 1e-5f;
constexpr int ROWS = 32;                 // rows per colsum block
constexpr int NBLK = Nn / ROWS;          // 128 partial blocks per batch

// ---------------- kernel 1: partial column sums over N (no atomics) ----------
__global__ __launch_bounds__(256) void k_colsum(const float* __restrict__ x,
                                                float* __restrict__ partial) {
    int blk = blockIdx.x;                 // Bn * NBLK = 1024 blocks
    int b  = blk / NBLK;
    int n0 = (blk % NBLK) * ROWS;
    int c  = threadIdx.x * 4;
    const float* p = x + ((size_t)b * Nn + n0) * Cn + c;
    float4 acc = make_float4(0.f, 0.f, 0.f, 0.f);
    #pragma unroll 8
    for (int r = 0; r < ROWS; ++r) {
        float4 v = *reinterpret_cast<const float4*>(p + (size_t)r * Cn);
        acc.x += v.x; acc.y += v.y; acc.z += v.z; acc.w += v.w;
    }
    *reinterpret_cast<float4*>(partial + (size_t)blk * Cn + c) = acc;
}

// ------- kernel 2: ctx reduce + h = gelu(ctx @ W1 + b1); 4 j-slices/b -------
__global__ __launch_bounds__(256) void k_mlp1(const float* __restrict__ partial,
                                              const float* __restrict__ W1,
                                              const float* __restrict__ b1,
                                              float* __restrict__ h) {
    int b = blockIdx.x >> 2;             // 32 blocks: b*4 + slice
    int s = blockIdx.x & 3;
    int t = threadIdx.x;

    __shared__ float ctx[Cn];
    __shared__ float red[4][64];

    // phase 1: reduce NBLK partials for 4 channels per thread
    const float invN = 1.0f / (float)Nn;
    const float* pp = partial + (size_t)b * NBLK * Cn;
    float a0 = 0.f, a1 = 0.f, a2 = 0.f, a3 = 0.f;
    for (int p = 0; p < NBLK; ++p) {
        const float* row = pp + (size_t)p * Cn;
        a0 += row[t];
        a1 += row[t + 256];
        a2 += row[t + 512];
        a3 += row[t + 768];
    }
    ctx[t]       = a0 * invN;
    ctx[t + 256] = a1 * invN;
    ctx[t + 512] = a2 * invN;
    ctx[t + 768] = a3 * invN;
    __syncthreads();

    // phase 2: split-K GEMV for 64 columns of W1
    int jl = t & 63, kq = t >> 6;
    int j  = s * 64 + jl;
    const float* w1 = W1 + j;
    float a = 0.f;
    int c0 = kq * 256;
    #pragma unroll 4
    for (int cc = 0; cc < 256; ++cc)
        a = fmaf(ctx[c0 + cc], w1[(size_t)(c0 + cc) * Hn], a);
    red[kq][jl] = a;
    __syncthreads();

    if (t < 64) {
        int jj = s * 64 + t;
        float v = red[0][t] + red[1][t] + red[2][t] + red[3][t] + b1[jj];
        h[b * Hn + jj] = 0.5f * v * (1.0f + erff(v * 0.70710678118654752440f));
    }
}

// ------- kernel 3: kernels = h @ W2 + b2, stored transposed [B][K][C] -------
__global__ __launch_bounds__(256) void k_mlp2(const float* __restrict__ h,
                                              const float* __restrict__ W2,
                                              const float* __restrict__ b2,
                                              float* __restrict__ kern) {
    int b = blockIdx.y;                   // 8
    int m = blockIdx.x * 256 + threadIdx.x;  // 12 x-blocks -> [0, Cn*Kn)
    __shared__ float hs[Hn];
    hs[threadIdx.x] = h[b * Hn + threadIdx.x];
    __syncthreads();
    float a0 = b2[m], a1 = 0.f, a2 = 0.f, a3 = 0.f;
    const float* w2 = W2 + m;
    #pragma unroll 4
    for (int j = 0; j < Hn; j += 4) {
        a0 = fmaf(hs[j],     w2[(size_t)j       * (Cn * Kn)], a0);
        a1 = fmaf(hs[j + 1], w2[(size_t)(j + 1) * (Cn * Kn)], a1);
        a2 = fmaf(hs[j + 2], w2[(size_t)(j + 2) * (Cn * Kn)], a2);
        a3 = fmaf(hs[j + 3], w2[(size_t)(j + 3) * (Cn * Kn)], a3);
    }
    float val = (a0 + a1) + (a2 + a3);
    int c = m / Kn, k = m - c * Kn;
    kern[((size_t)b * Kn + k) * Cn + c] = val;
}

// ------- kernel 4: depthwise conv + residual + LayerNorm; 1 wave per row ----
// XCD-chunk swizzle: consecutive rows stay on one XCD so the 3x neighbor-row
// reuse (x[n-1], x[n], x[n+1]) hits that XCD's private L2.
__global__ __launch_bounds__(256) void k_conv_ln(const float* __restrict__ x,
                                                 const float* __restrict__ kern,
                                                 const float* __restrict__ gamma,
                                                 const float* __restrict__ beta,
                                                 float* __restrict__ out) {
    int bid = blockIdx.x;                          // 8192 blocks (divisible by 8)
    int nb8 = gridDim.x >> 3;                      // blocks per XCD chunk
    int sb  = (bid & 7) * nb8 + (bid >> 3);        // bijective chunk swizzle
    int r = sb * 4 + (threadIdx.x >> 6);           // global row, Bn*Nn total
    int b = r >> 12;                               // Nn == 4096
    int n = r & (Nn - 1);
    int lane = threadIdx.x & 63;

    const float4* xc4 = reinterpret_cast<const float4*>(x + (size_t)r * Cn);
    const float4* xm4 = xc4 - (Cn / 4);
    const float4* xp4 = xc4 + (Cn / 4);
    const float4* k04 = reinterpret_cast<const float4*>(kern + (size_t)b * Kn * Cn);
    const float4* k14 = k04 + (Cn / 4);
    const float4* k24 = k14 + (Cn / 4);

    bool hasM = (n > 0), hasP = (n < Nn - 1);
    float4 y[4];
    float s = 0.f, s2 = 0.f;
    #pragma unroll
    for (int k = 0; k < 4; ++k) {
        int ci = lane + (k << 6);                   // float4 index within row
        float4 xc = xc4[ci];
        float4 xm = hasM ? xm4[ci] : make_float4(0.f, 0.f, 0.f, 0.f);
        float4 xp = hasP ? xp4[ci] : make_float4(0.f, 0.f, 0.f, 0.f);
        float4 k0 = k04[ci], k1 = k14[ci], k2 = k24[ci];
        float4 v;
        v.x = fmaf(k0.x, xm.x, fmaf(k1.x, xc.x, fmaf(k2.x, xp.x, xc.x)));
        v.y = fmaf(k0.y, xm.y, fmaf(k1.y, xc.y, fmaf(k2.y, xp.y, xc.y)));
        v.z = fmaf(k0.z, xm.z, fmaf(k1.z, xc.z, fmaf(k2.z, xp.z, xc.z)));
        v.w = fmaf(k0.w, xm.w, fmaf(k1.w, xc.w, fmaf(k2.w, xp.w, xc.w)));
        y[k] = v;
        s  += (v.x + v.y) + (v.z + v.w);
        s2 += fmaf(v.x, v.x, fmaf(v.y, v.y, fmaf(v.z, v.z, v.w * v.w)));
    }

    // 64-lane butterfly reduction (no LDS, no barrier)
    #pragma unroll
    for (int off = 1; off < 64; off <<= 1) {
        s  += __shfl_xor(s,  off, 64);
        s2 += __shfl_xor(s2, off, 64);
    }

    float mu   = s * (1.0f / (float)Cn);
    float var  = fmaf(-mu, mu, s2 * (1.0f / (float)Cn));
    float rstd = rsqrtf(var + EPS);

    const float4* g4  = reinterpret_cast<const float4*>(gamma);
    const float4* be4 = reinterpret_cast<const float4*>(beta);
    float4* o4 = reinterpret_cast<float4*>(out + (size_t)r * Cn);
    #pragma unroll
    for (int k = 0; k < 4; ++k) {
        int ci = lane + (k << 6);
        float4 g = g4[ci], be = be4[ci], v = y[k], o;
        o.x = fmaf((v.x - mu) * rstd, g.x, be.x);
        o.y = fmaf((v.y - mu) * rstd, g.y, be.y);
        o.z = fmaf((v.z - mu) * rstd, g.z, be.z);
        o.w = fmaf((v.w - mu) * rstd, g.w, be.w);
        o4[ci] = o;
    }
}

extern "C" void kernel_launch(void* const* d_in, const int* in_sizes, int n_in,
                              void* d_out, int out_size, void* d_ws, size_t ws_size,
                              hipStream_t stream) {
    const float* x     = (const float*)d_in[0];
    const float* W1    = (const float*)d_in[1];
    const float* b1    = (const float*)d_in[2];
    const float* W2    = (const float*)d_in[3];
    const float* b2    = (const float*)d_in[4];
    const float* gamma = (const float*)d_in[5];
    const float* beta  = (const float*)d_in[6];
    float* out = (float*)d_out;

    float* ws      = (float*)d_ws;
    float* partial = ws;                                  // 1024*1024 floats (4 MB)
    float* h       = partial + (size_t)Bn * NBLK * Cn;    // 2048 floats
    float* kern    = h + Bn * Hn;                         // 24576 floats

    k_colsum<<<Bn * NBLK, 256, 0, stream>>>(x, partial);
    k_mlp1<<<Bn * 4, 256, 0, stream>>>(partial, W1, b1, h);
    dim3 g2(Cn * Kn / 256, Bn);
    k_mlp2<<<g2, 256, 0, stream>>>(h, W2, b2, kern);
    k_conv_ln<<<Bn * Nn / 4, 256, 0, stream>>>(x, kern, gamma, beta, out);
}